// Round 9
// baseline (1115.875 us; speedup 1.0000x reference)
//
#include <hip/hip_runtime.h>
#include <math.h>

// RelationalMemoryCell: B=2048, S=8, H=8, M=1024, QKV=384, TOTAL=3072,
// IN_DIM=1024. fp32 in/out; GEMMs bf16 MFMA (fp32 accumulate).
//
// R15: nine structures bracket the space; the only variable that tracks
// efficiency is per-block work (m102 shape-curve: small-K collapse).
// gemm256x128: tall 256x128/BK=32 tile, 8 waves, 2-buffer, 48KB LDS ->
// 3 blocks/CU, uniform 3 loads/thread + counted vmcnt(3). Doubles
// per-block FLOPs vs 128^2 while keeping multi-block residency (gemm256's
// 128KB couldn't). mlp grid = 512 blocks = one fully-resident round.
// Also: qkv chunk merge Bc<=2048 (one gemm256 + one attn dispatch).

typedef unsigned short ushort_t;                                  // bf16 bits
typedef short bf16x8_t __attribute__((ext_vector_type(8)));       // MFMA A/B frag
typedef float f32x4_t  __attribute__((ext_vector_type(4)));       // MFMA C/D frag

#define MFMA16(a, b, c) __builtin_amdgcn_mfma_f32_16x16x32_bf16((a), (b), (c), 0, 0, 0)

__device__ __forceinline__ ushort_t f2bf(float f) {               // RNE
    unsigned int u = __float_as_uint(f);
    u += 0x7fff + ((u >> 16) & 1);
    return (ushort_t)(u >> 16);
}
__device__ __forceinline__ float bf2f(ushort_t h) {
    return __uint_as_float(((unsigned int)h) << 16);
}
__device__ __forceinline__ float fast_tanh(float x) {             // sat-safe
    float e = __expf(2.0f * x);
    return 1.0f - 2.0f * __builtin_amdgcn_rcpf(e + 1.0f);
}
__device__ __forceinline__ float fast_sigmoid(float x) {
    return __builtin_amdgcn_rcpf(1.0f + __expf(-x));
}

__device__ __forceinline__ void load_lds_16(const void* g, void* l) {
    __builtin_amdgcn_global_load_lds(
        (const __attribute__((address_space(1))) void*)g,
        (__attribute__((address_space(3))) void*)l, 16, 0, 0);
}

// ---------------------------------------------------------------------------
// Tall 256x128 bf16 GEMM, BK=32, 8 waves (512 thr), 2-buffer, 3 blocks/CU.
// A: MxK bf16 row-major, Wt: NxK bf16 (W^T). K%64==0.
// Wave w: rows wr=(w>>1)*64, cols wc=(w&1)*64; 4x4 16x16 frags per wave.
// Stage per tile: A 1024 chunks (2/thread) + B 512 chunks (1/thread) =
// uniform 3 loads/thread. Loop: vmcnt(3) [tile t landed, t+1's 3 in
// flight] -> barrier -> ds_read 8xb128 -> lgkmcnt(0) -> barrier -> pin ->
// stage(t+2 -> buf just consumed) -> 16 MFMA. vmcnt never 0 mid-loop.
// Chunk-XOR swizzle pair identical to R0-R8 (bank-conflict-free verified).
// Epilogue modes: outp -> ig*tanh(v+res)+fg*bf16mem ; Cb -> bf16 ; Cf -> fp32.
// memb (bf16 mem rows in mpi layout): row b*8+s -> mpi row row+(row>>3).
// ---------------------------------------------------------------------------
__global__ __launch_bounds__(512, 6)
void gemm256x128(const ushort_t* __restrict__ A, const ushort_t* __restrict__ Wt,
                 const float* __restrict__ bias, float* __restrict__ Cf,
                 ushort_t* __restrict__ Cb, const ushort_t* __restrict__ resb,
                 const float* __restrict__ igfg, const ushort_t* __restrict__ memb,
                 float* __restrict__ outp, int N, int K, int relu,
                 int ncol, int nrow)
{
    __shared__ __align__(16) ushort_t As[2][256][32];   // 32 KiB
    __shared__ __align__(16) ushort_t Bs[2][128][32];   // 16 KiB
    const int tid  = threadIdx.x;
    const int wave = tid >> 6, lane = tid & 63;
    const int lrow  = lane & 15;
    const int lquad = lane >> 4;
    const int wr = (wave >> 1) * 64;    // 0,64,128,192
    const int wc = (wave & 1)  * 64;    // 0,64

    // XCD-aware tile decode (row-tile's col-blocks at stride-8 ids -> same XCD)
    int l = blockIdx.x, rT, cT;
    if ((nrow & 7) == 0) {
        int group = l / (8 * ncol);
        int w     = l - group * 8 * ncol;
        rT = group * 8 + (w & 7);
        cT = w >> 3;
    } else {
        rT = l / ncol;
        cT = l - rT * ncol;
    }
    const int rowBase = rT * 256;
    const int colBase = cT * 128;

    // stage tile at k-offset k0 into buffer b: exactly 3 gload_lds/thread.
    auto stage = [&](int k0, int b) {
        #pragma unroll
        for (int i = 0; i < 2; ++i) {                    // A: 1024 chunks
            int e   = i * 512 + tid;
            int row = e >> 2, sl = e & 3;
            int gc  = sl ^ ((row >> 1) & 3);
            load_lds_16(A + (size_t)(rowBase + row) * K + k0 + gc * 8,
                        &As[b][row][sl * 8]);
        }
        {                                                // B: 512 chunks
            int e   = tid;
            int row = e >> 2, sl = e & 3;
            int gc  = sl ^ ((row >> 1) & 3);
            load_lds_16(Wt + (size_t)(colBase + row) * K + k0 + gc * 8,
                        &Bs[b][row][sl * 8]);
        }
    };

    const int NT = K >> 5;                  // K-steps of 32 (NT>=2)

    stage(0, 0);
    asm volatile("" ::: "memory");          // keep issue order = tile order
    stage(32, 1);

    f32x4_t acc[4][4] = {};

    for (int t = 0; t < NT; ++t) {
        const int b = t & 1;
        if (t + 1 < NT)
            asm volatile("s_waitcnt vmcnt(3)" ::: "memory");  // tile t landed
        else
            asm volatile("s_waitcnt vmcnt(0)" ::: "memory");
        __builtin_amdgcn_s_barrier();       // all waves: tile t visible

        bf16x8_t af[4], bfr[4];
        #pragma unroll
        for (int q = 0; q < 4; ++q) {
            int ma = wr + q * 16 + lrow;                  // 0..255
            int pa = lquad ^ ((ma >> 1) & 3);
            af[q]  = *(const bf16x8_t*)&As[b][ma][pa * 8];
            int nb = wc + q * 16 + lrow;                  // 0..127
            int pb = lquad ^ ((nb >> 1) & 3);
            bfr[q] = *(const bf16x8_t*)&Bs[b][nb][pb * 8];
        }
        asm volatile("s_waitcnt lgkmcnt(0)" ::: "memory");    // frags in regs
        __builtin_amdgcn_s_barrier();       // all waves done reading buf b
        __builtin_amdgcn_sched_barrier(0);  // pin: stage stays below barrier
        if (t + 2 < NT) stage((t + 2) * 32, b);               // refill buf b

        #pragma unroll
        for (int mi = 0; mi < 4; ++mi)
            #pragma unroll
            for (int ni = 0; ni < 4; ++ni)
                acc[mi][ni] = MFMA16(af[mi], bfr[ni], acc[mi][ni]);
    }

    // D layout: col = lane&15, row = lquad*4 + r   [m89/m91]
    #pragma unroll
    for (int mi = 0; mi < 4; ++mi) {
        #pragma unroll
        for (int ni = 0; ni < 4; ++ni) {
            int col = colBase + wc + ni * 16 + lrow;
            float bv = bias[col];
            #pragma unroll
            for (int r = 0; r < 4; ++r) {
                int row = rowBase + wr + mi * 16 + lquad * 4 + r;
                size_t idx = (size_t)row * N + col;
                float v = acc[mi][ni][r] + bv;
                if (resb) v += bf2f(resb[idx]);
                if (relu) v = fmaxf(v, 0.f);
                if (outp) {
                    float ig = igfg[row * 2], fg = igfg[row * 2 + 1];
                    float mv = bf2f(memb[(size_t)(row + (row >> 3)) * N + col]);
                    outp[idx] = ig * fast_tanh(v) + fg * mv;
                } else if (Cb) {
                    Cb[idx] = f2bf(v);
                } else {
                    Cf[idx] = v;
                }
            }
        }
    }
}

// ---------------------------------------------------------------------------
// 256x256 8-phase bf16 GEMM (qkv only; control arm).
// ---------------------------------------------------------------------------
__global__ __launch_bounds__(512, 2)
void gemm256(const ushort_t* __restrict__ A, const ushort_t* __restrict__ Wt,
             const float* __restrict__ bias, ushort_t* __restrict__ Cb,
             int N, int K, int ncol, int nrow)
{
    __shared__ __align__(16) ushort_t As[2][256][64];   // 64 KiB
    __shared__ __align__(16) ushort_t Bs[2][256][64];   // 64 KiB

    const int tid   = threadIdx.x;
    const int wave  = tid >> 6, lane = tid & 63;
    const int lrow  = lane & 15, lquad = lane >> 4;
    const int wr    = (wave >> 2) * 64;
    const int wc    = (wave & 3) * 32;

    const int nwg = ncol * nrow;
    int l = blockIdx.x;
    int q = nwg >> 3, r = nwg & 7;
    int xcd = l & 7, ib = l >> 3;
    int wg = (xcd < r) ? xcd * (q + 1) + ib : r * (q + 1) + (xcd - r) * q + ib;
    int rT = wg / ncol, cT = wg - rT * ncol;
    const int rowBase = rT * 256;
    const int colBase = cT * 256;

    const int NT = K >> 6;

    auto stage = [&](const ushort_t* __restrict__ G, int gbase, int kt,
                     int half, ushort_t (*lds)[64]) {
        #pragma unroll
        for (int j = 0; j < 2; ++j) {
            int ci   = j * 512 + tid;
            int rl   = ci >> 3;
            int slot = ci & 7;
            int row  = half * 128 + rl;
            int gc   = slot ^ (rl & 7);
            const ushort_t* g = G + (size_t)(gbase + row) * K + kt * 64 + gc * 8;
            load_lds_16(g, &lds[row][slot * 8]);
        }
    };

    stage(A,  rowBase, 0, 0, As[0]);
    stage(A,  rowBase, 0, 1, As[0]);
    stage(Wt, colBase, 0, 0, Bs[0]);
    stage(Wt, colBase, 0, 1, Bs[0]);
    asm volatile("" ::: "memory");
    stage(A,  rowBase, 1, 0, As[1]);
    stage(Wt, colBase, 1, 0, Bs[1]);
    asm volatile("s_waitcnt vmcnt(4)" ::: "memory");
    __builtin_amdgcn_s_barrier();

    f32x4_t acc[8][4] = {};
    bf16x8_t af[4][2], bfr[4][2];
    const int s0 = (lquad ^ (lrow & 7)) * 8;
    const int s1 = ((lquad ^ (lrow & 7)) ^ 4) * 8;

    for (int t = 0; t < NT; ++t) {
        const int bf = t & 1, nf = bf ^ 1;
        ushort_t (*Ab)[64] = As[bf];
        ushort_t (*Bb)[64] = Bs[bf];

        #pragma unroll
        for (int m = 0; m < 4; ++m) {
            int ra = wr + m * 16 + lrow;
            af[m][0] = *(const bf16x8_t*)&Ab[ra][s0];
            af[m][1] = *(const bf16x8_t*)&Ab[ra][s1];
        }
        #pragma unroll
        for (int n = 0; n < 2; ++n) {
            int rb = wc + n * 16 + lrow;
            bfr[n][0] = *(const bf16x8_t*)&Bb[rb][s0];
            bfr[n][1] = *(const bf16x8_t*)&Bb[rb][s1];
        }
        if (t + 1 < NT) stage(A, rowBase, t + 1, 1, As[nf]);
        __builtin_amdgcn_s_barrier();
        asm volatile("s_waitcnt lgkmcnt(0)" ::: "memory");
        __builtin_amdgcn_s_setprio(1);
        #pragma unroll
        for (int m = 0; m < 4; ++m)
            #pragma unroll
            for (int n = 0; n < 2; ++n) {
                acc[m][n] = MFMA16(af[m][0], bfr[n][0], acc[m][n]);
                acc[m][n] = MFMA16(af[m][1], bfr[n][1], acc[m][n]);
            }
        __builtin_amdgcn_s_setprio(0);
        __builtin_amdgcn_s_barrier();

        #pragma unroll
        for (int n = 0; n < 2; ++n) {
            int rb = 128 + wc + n * 16 + lrow;
            bfr[2 + n][0] = *(const bf16x8_t*)&Bb[rb][s0];
            bfr[2 + n][1] = *(const bf16x8_t*)&Bb[rb][s1];
        }
        if (t + 1 < NT) stage(Wt, colBase, t + 1, 1, Bs[nf]);
        __builtin_amdgcn_s_barrier();
        asm volatile("s_waitcnt lgkmcnt(0)" ::: "memory");
        __builtin_amdgcn_s_setprio(1);
        #pragma unroll
        for (int m = 0; m < 4; ++m)
            #pragma unroll
            for (int n = 0; n < 2; ++n) {
                acc[m][2 + n] = MFMA16(af[m][0], bfr[2 + n][0], acc[m][2 + n]);
                acc[m][2 + n] = MFMA16(af[m][1], bfr[2 + n][1], acc[m][2 + n]);
            }
        __builtin_amdgcn_s_setprio(0);
        __builtin_amdgcn_s_barrier();

        #pragma unroll
        for (int m = 0; m < 4; ++m) {
            int ra = 128 + wr + m * 16 + lrow;
            af[m][0] = *(const bf16x8_t*)&Ab[ra][s0];
            af[m][1] = *(const bf16x8_t*)&Ab[ra][s1];
        }
        if (t + 2 < NT) stage(A, rowBase, t + 2, 0, As[bf]);
        __builtin_amdgcn_s_barrier();
        asm volatile("s_waitcnt lgkmcnt(0)" ::: "memory");
        __builtin_amdgcn_s_setprio(1);
        #pragma unroll
        for (int m = 0; m < 4; ++m)
            #pragma unroll
            for (int n = 0; n < 2; ++n) {
                acc[4 + m][n] = MFMA16(af[m][0], bfr[n][0], acc[4 + m][n]);
                acc[4 + m][n] = MFMA16(af[m][1], bfr[n][1], acc[4 + m][n]);
            }
        __builtin_amdgcn_s_setprio(0);
        __builtin_amdgcn_s_barrier();

        if (t + 2 < NT) {
            stage(Wt, colBase, t + 2, 0, Bs[bf]);
            asm volatile("s_waitcnt vmcnt(4)" ::: "memory");
        } else if (t + 1 < NT) {
            asm volatile("s_waitcnt vmcnt(0)" ::: "memory");
        }
        __builtin_amdgcn_s_barrier();
        __builtin_amdgcn_s_setprio(1);
        #pragma unroll
        for (int m = 0; m < 4; ++m)
            #pragma unroll
            for (int n = 0; n < 2; ++n) {
                acc[4 + m][2 + n] = MFMA16(af[m][0], bfr[2 + n][0], acc[4 + m][2 + n]);
                acc[4 + m][2 + n] = MFMA16(af[m][1], bfr[2 + n][1], acc[4 + m][2 + n]);
            }
        __builtin_amdgcn_s_setprio(0);
        __builtin_amdgcn_s_barrier();
    }

    #pragma unroll
    for (int mi = 0; mi < 8; ++mi) {
        #pragma unroll
        for (int ni = 0; ni < 4; ++ni) {
            int col = colBase + wc + (ni & 1) * 16 + ((ni >> 1) << 7) + lrow;
            float bv = bias[col];
            #pragma unroll
            for (int rr = 0; rr < 4; ++rr) {
                int row = rowBase + wr + (mi & 3) * 16 + ((mi >> 2) << 7)
                        + lquad * 4 + rr;
                size_t idx = (size_t)row * N + col;
                Cb[idx] = f2bf(acc[mi][ni][rr] + bv);
            }
        }
    }
}

// ---------------------------------------------------------------------------
// fp32 -> bf16 elementwise
// ---------------------------------------------------------------------------
__global__ __launch_bounds__(256)
void conv_bf16(const float* __restrict__ in, ushort_t* __restrict__ out, size_t n)
{
    size_t i = ((size_t)blockIdx.x * 256 + threadIdx.x) * 4;
    if (i >= n) return;
    float4 v = *(const float4*)(in + i);
    out[i + 0] = f2bf(v.x); out[i + 1] = f2bf(v.y);
    out[i + 2] = f2bf(v.z); out[i + 3] = f2bf(v.w);
}

// ---------------------------------------------------------------------------
// Weight transpose+convert, all 4 weights in one launch.
// x-ranges: [0,32)=kernel_in, [32,128)=kernel_qkv, [128,160)=k0, [160,192)=k1
// ---------------------------------------------------------------------------
__global__ __launch_bounds__(256)
void conv_wt4(const float* __restrict__ W0, ushort_t* __restrict__ T0,
              const float* __restrict__ W1, ushort_t* __restrict__ T1,
              const float* __restrict__ W2, ushort_t* __restrict__ T2,
              const float* __restrict__ W3, ushort_t* __restrict__ T3)
{
    __shared__ float t[32][33];
    int bx = blockIdx.x;
    const float* W; ushort_t* T; int N;
    if (bx < 32)       { W = W0; T = T0; N = 1024; }
    else if (bx < 128) { W = W1; T = T1; N = 3072; bx -= 32; }
    else if (bx < 160) { W = W2; T = T2; N = 1024; bx -= 128; }
    else               { W = W3; T = T3; N = 1024; bx -= 160; }
    const int K = 1024;
    const int n0 = bx * 32, k0 = blockIdx.y * 32;
    const int tx = threadIdx.x & 31, ty = threadIdx.x >> 5;   // (32, 8)
    #pragma unroll
    for (int i = 0; i < 4; ++i)
        t[ty * 4 + i][tx] = W[(size_t)(k0 + ty * 4 + i) * N + n0 + tx];
    __syncthreads();
    #pragma unroll
    for (int i = 0; i < 4; ++i)
        T[(size_t)(n0 + ty * 4 + i) * K + k0 + tx] = f2bf(t[tx][ty * 4 + i]);
}

// ---------------------------------------------------------------------------
// prep: block per mpi row (b*9+s). s<8: mem row -> mpi bf16 + fused gates
// reduction tanh(mem).kgm -> igfg. s==8: copy x_b row.
// ---------------------------------------------------------------------------
__global__ __launch_bounds__(256)
void prep_kernel(const float* __restrict__ mem, const ushort_t* __restrict__ xb,
                 const float* __restrict__ kgm, const float* __restrict__ bgm,
                 const float* __restrict__ gi, ushort_t* __restrict__ mpi,
                 float* __restrict__ igfg)
{
    const int row = blockIdx.x;            // b*9+s
    const int tid = threadIdx.x;
    const int b = row / 9, s = row - b * 9;
    if (s == 8) {
        ((ushort4*)(mpi + (size_t)row * 1024))[tid] =
            ((const ushort4*)(xb + (size_t)b * 1024))[tid];
        return;
    }
    const float* mrow = mem + ((size_t)b * 8 + s) * 1024;
    float4 v = ((const float4*)mrow)[tid];
    ushort4 o;
    o.x = f2bf(v.x); o.y = f2bf(v.y); o.z = f2bf(v.z); o.w = f2bf(v.w);
    ((ushort4*)(mpi + (size_t)row * 1024))[tid] = o;
    float4 k0 = ((const float4*)kgm)[tid * 2];
    float4 k1 = ((const float4*)kgm)[tid * 2 + 1];
    float t0 = fast_tanh(v.x), t1 = fast_tanh(v.y);
    float t2 = fast_tanh(v.z), t3 = fast_tanh(v.w);
    float g0 = t0 * k0.x + t1 * k0.z + t2 * k1.x + t3 * k1.z;
    float g1 = t0 * k0.y + t1 * k0.w + t2 * k1.y + t3 * k1.w;
    #pragma unroll
    for (int m = 1; m <= 32; m <<= 1) {
        g0 += __shfl_xor(g0, m);
        g1 += __shfl_xor(g1, m);
    }
    __shared__ float wg[4][2];
    if ((tid & 63) == 0) { wg[tid >> 6][0] = g0; wg[tid >> 6][1] = g1; }
    __syncthreads();
    if (tid == 0) {
        float G0 = wg[0][0] + wg[1][0] + wg[2][0] + wg[3][0];
        float G1 = wg[0][1] + wg[1][1] + wg[2][1] + wg[3][1];
        int orow = b * 8 + s;
        igfg[orow * 2 + 0] = fast_sigmoid(G0 + bgm[0] + gi[b * 2 + 0]);
        igfg[orow * 2 + 1] = fast_sigmoid(G1 + bgm[1] + gi[b * 2 + 1] + 1.0f);
    }
}

// ---------------------------------------------------------------------------
// MFMA attention: block per (b,h), 256 thr. Residual from mpi bf16.
// ---------------------------------------------------------------------------
__global__ __launch_bounds__(256)
void attn_kernel(const ushort_t* __restrict__ qkv, const ushort_t* __restrict__ mpib,
                 ushort_t* __restrict__ m1b)
{
    const int bh = blockIdx.x;
    const int b = bh >> 3, h = bh & 7;
    constexpr int VS = 40;                            // padded j-stride
    __shared__ __align__(16) ushort_t vt[128 * VS];   // V^T [d][j]
    __shared__ __align__(16) ushort_t pw[16 * VS];    // P [i][j]
    const int tid  = threadIdx.x;
    const int lane = tid & 63, wave = tid >> 6;
    const int quad = lane >> 4;
    const size_t qrow0 = (size_t)b * 9;

    {
        unsigned long long* z = (unsigned long long*)vt;
        #pragma unroll
        for (int i = 0; i < 5; ++i) z[tid + i * 256] = 0ull;
        if (tid < 160) ((unsigned long long*)pw)[tid] = 0ull;
    }
    __syncthreads();
    for (int c = tid; c < 9 * 128; c += 256) {
        int j = c >> 7, d = c & 127;
        vt[d * VS + j] = qkv[(qrow0 + j) * 3072 + (size_t)h * 384 + 256 + d];
    }

    f32x4_t sacc = {0.f, 0.f, 0.f, 0.f};
    if (wave == 0) {
        const int m  = lane & 7;
        const int n  = lane & 15;
        const int nc = n > 8 ? 8 : n;
        const ushort_t* qb = qkv + (qrow0 + m)  * 3072 + (size_t)h * 384 + quad * 8;
        const ushort_t* kb = qkv + (qrow0 + nc) * 3072 + (size_t)h * 384 + 128 + quad * 8;
        #pragma unroll
        for (int t = 0; t < 4; ++t) {
            bf16x8_t aq = *(const bf16x8_t*)(qb + t * 32);
            bf16x8_t bk = *(const bf16x8_t*)(kb + t * 32);
            sacc = __builtin_amdgcn_mfma_f32_16x16x32_bf16(aq, bk, sacc, 0, 0, 0);
        }
    }
    __syncthreads();

    if (wave == 0) {
        const int j = lane & 15;
        const float scale = 0.05103103630798288f;      // 384^-0.5
        #pragma unroll
        for (int r = 0; r < 4; ++r) {
            float sv = (j < 9) ? sacc[r] * scale : -1e30f;
            float mx = sv;
            mx = fmaxf(mx, __shfl_xor(mx, 1));
            mx = fmaxf(mx, __shfl_xor(mx, 2));
            mx = fmaxf(mx, __shfl_xor(mx, 4));
            mx = fmaxf(mx, __shfl_xor(mx, 8));
            float e = (j < 9) ? __expf(sv - mx) : 0.f;
            float sum = e;
            sum += __shfl_xor(sum, 1);
            sum += __shfl_xor(sum, 2);
            sum += __shfl_xor(sum, 4);
            sum += __shfl_xor(sum, 8);
            pw[(quad * 4 + r) * VS + j] = f2bf(e * __builtin_amdgcn_rcpf(sum));
        }
    }
    __syncthreads();

    {
        const int n  = lane & 15;
        const int d0 = wave * 32;
        bf16x8_t pa = *(const bf16x8_t*)&pw[n * VS + quad * 8];
        #pragma unroll
        for (int g = 0; g < 2; ++g) {
            int d = d0 + g * 16 + n;
            bf16x8_t vb = *(const bf16x8_t*)&vt[d * VS + quad * 8];
            f32x4_t o = {0.f, 0.f, 0.f, 0.f};
            o = __builtin_amdgcn_mfma_f32_16x16x32_bf16(pa, vb, o, 0, 0, 0);
            #pragma unroll
            for (int r = 0; r < 4; ++r) {
                int i = quad * 4 + r;
                if (i < 8) {
                    float mv = bf2f(mpib[((size_t)b * 9 + i) * 1024 + (size_t)h * 128 + d]);
                    size_t idx = ((size_t)b * 8 + i) * 1024 + (size_t)h * 128 + d;
                    m1b[idx] = f2bf(o[r] + mv);
                }
            }
        }
    }
}

// ---------------------------------------------------------------------------
// gi[b][g] = x_b[b,:] . kernel_gi[:,g] + bias_gi[g]
// ---------------------------------------------------------------------------
__global__ __launch_bounds__(256)
void gi_kernel(const ushort_t* __restrict__ xb, const float* __restrict__ kgi,
               const float* __restrict__ bgi, float* __restrict__ gi)
{
    const int b = blockIdx.x, tid = threadIdx.x;
    float g0 = 0.f, g1 = 0.f;
    for (int k = tid; k < 1024; k += 256) {
        float xv = bf2f(xb[(size_t)b * 1024 + k]);
        g0 += xv * kgi[k * 2];
        g1 += xv * kgi[k * 2 + 1];
    }
    #pragma unroll
    for (int m = 1; m <= 32; m <<= 1) {
        g0 += __shfl_xor(g0, m);
        g1 += __shfl_xor(g1, m);
    }
    __shared__ float wg[4][2];
    if ((tid & 63) == 0) { wg[tid >> 6][0] = g0; wg[tid >> 6][1] = g1; }
    __syncthreads();
    if (tid == 0) {
        gi[b * 2 + 0] = wg[0][0] + wg[1][0] + wg[2][0] + wg[3][0] + bgi[0];
        gi[b * 2 + 1] = wg[0][1] + wg[1][1] + wg[2][1] + wg[3][1] + bgi[1];
    }
}

// ---------------------------------------------------------------------------
extern "C" void kernel_launch(void* const* d_in, const int* in_sizes, int n_in,
                              void* d_out, int out_size, void* d_ws, size_t ws_size,
                              hipStream_t stream)
{
    const float* inputs     = (const float*)d_in[0];
    const float* memory     = (const float*)d_in[1];
    const float* kernel_qkv = (const float*)d_in[2];
    const float* bias_qkv   = (const float*)d_in[3];
    const float* kernel_gi  = (const float*)d_in[4];
    const float* bias_gi    = (const float*)d_in[5];
    const float* kernel_gm  = (const float*)d_in[6];
    const float* bias_gm    = (const float*)d_in[7];
    const float* kernel_in  = (const float*)d_in[8];
    const float* bias_in    = (const float*)d_in[9];
    const float* mlp_k0     = (const float*)d_in[10];
    const float* mlp_b0     = (const float*)d_in[11];
    const float* mlp_k1     = (const float*)d_in[12];
    const float* mlp_b1     = (const float*)d_in[13];
    float* out = (float*)d_out;

    // ---- workspace carve (bytes) ----
    char* p = (char*)d_ws;
    ushort_t* in_b   = (ushort_t*)p;  p += (size_t)2048 * 1024 * 2;    // 4 MB
    ushort_t* x_b    = (ushort_t*)p;  p += (size_t)2048 * 1024 * 2;    // 4 MB
    ushort_t* wt_in  = (ushort_t*)p;  p += (size_t)1024 * 1024 * 2;    // 2 MB
    ushort_t* wt_qkv = (ushort_t*)p;  p += (size_t)3072 * 1024 * 2;    // 6 MB
    ushort_t* wt_k0  = (ushort_t*)p;  p += (size_t)1024 * 1024 * 2;
    ushort_t* wt_k1  = (ushort_t*)p;  p += (size_t)1024 * 1024 * 2;
    float*    ws_gi  = (float*)p;     p += (size_t)2048 * 2 * 4;
    float*    igfg   = (float*)p;     p += (size_t)16384 * 2 * 4;      // 128 KB
    ushort_t* ws_mpi = (ushort_t*)p;  p += (size_t)18432 * 1024 * 2;   // 36 MB
    ushort_t* m1b    = (ushort_t*)p;  p += (size_t)16384 * 1024 * 2;   // 32 MB
    ushort_t* ws_h   = (ushort_t*)p;  p += (size_t)16384 * 1024 * 2;   // 32 MB
    size_t fixed = (size_t)(p - (char*)d_ws);

    // Bc*9 must be divisible by 256 for the 256^2 kernel => Bc >= 256.
    // Try full-batch first (one qkv + one attn dispatch).
    int Bc = 256;
    for (int cand = 2048; cand >= 256; cand >>= 1)
        if (fixed + (size_t)cand * 9 * 3072 * 2 <= ws_size) { Bc = cand; break; }
    ushort_t* ws_qkv = (ushort_t*)p;   // Bc*9*3072 bf16

    // ---- conversions ----
    conv_bf16<<<2048, 256, 0, stream>>>(inputs, in_b, (size_t)2048 * 1024);
    conv_wt4<<<dim3(192, 32), 256, 0, stream>>>(
        kernel_in, wt_in, kernel_qkv, wt_qkv, mlp_k0, wt_k0, mlp_k1, wt_k1);

    // x_b = bf16(inputs @ kernel_in + bias_in)   (tall 256x128, 64 blocks)
    gemm256x128<<<8 * 8, 512, 0, stream>>>(
        in_b, wt_in, bias_in, nullptr, x_b, nullptr, nullptr, nullptr, nullptr,
        1024, 1024, 0, 8, 8);

    gi_kernel<<<2048, 256, 0, stream>>>(x_b, kernel_gi, bias_gi, ws_gi);
    prep_kernel<<<18432, 256, 0, stream>>>(memory, x_b, kernel_gm, bias_gm,
                                           ws_gi, ws_mpi, igfg);

    // qkv + attention, chunked (256^2 8-phase GEMM; Bc=2048 => single pass)
    const int NC = 2048 / Bc;
    for (int c = 0; c < NC; ++c) {
        const int b0 = c * Bc;
        const int nrow = Bc * 9 / 256;
        gemm256<<<12 * nrow, 512, 0, stream>>>(
            ws_mpi + (size_t)b0 * 9 * 1024, wt_qkv, bias_qkv, ws_qkv,
            3072, 1024, 12, nrow);
        attn_kernel<<<Bc * 8, 256, 0, stream>>>(
            ws_qkv, ws_mpi + (size_t)b0 * 9 * 1024, m1b + (size_t)b0 * 8192);
    }

    // h = relu(m1 @ mlp_k0 + mlp_b0)   (tall 256x128: 512 blocks, 2/CU, 1 round)
    gemm256x128<<<64 * 8, 512, 0, stream>>>(
        m1b, wt_k0, mlp_b0, nullptr, ws_h, nullptr, nullptr, nullptr, nullptr,
        1024, 1024, 1, 8, 64);

    // out = ig*tanh(m1 + h @ mlp_k1 + mlp_b1) + fg*mem(bf16 via mpi), fused
    gemm256x128<<<64 * 8, 512, 0, stream>>>(
        ws_h, wt_k1, mlp_b1, nullptr, nullptr, m1b, igfg, ws_mpi, out,
        1024, 1024, 0, 8, 64);
}

// Round 10
// 505.346 us; speedup vs baseline: 2.2081x; 2.2081x over previous
//
#include <hip/hip_runtime.h>
#include <math.h>

// RelationalMemoryCell: B=2048, S=8, H=8, M=1024, QKV=384, TOTAL=3072,
// IN_DIM=1024. fp32 in/out; GEMMs bf16 MFMA (fp32 accumulate).
//
// R16: R9's tall-tile test was voided by a self-inflicted spill —
// __launch_bounds__(512,6) capped VGPRs at 40 < the 64 needed for acc
// alone => 1 GB/dispatch scratch traffic (WRITE_SIZE 1.04e6 KB, MfmaUtil
// 3.9%). Fixed: __launch_bounds__(512) (no min-waves force; ~100-130
// VGPRs, 2 blocks/CU by both VGPR and 48KB-LDS budgets). Tall 256x128
// tile retested on mlp0/mlp1 only; x back on gemm128p3; qkv reverted to
// R8's chunked gemm256 control (Bc=256).

typedef unsigned short ushort_t;                                  // bf16 bits
typedef short bf16x8_t __attribute__((ext_vector_type(8)));       // MFMA A/B frag
typedef float f32x4_t  __attribute__((ext_vector_type(4)));       // MFMA C/D frag

#define MFMA16(a, b, c) __builtin_amdgcn_mfma_f32_16x16x32_bf16((a), (b), (c), 0, 0, 0)

__device__ __forceinline__ ushort_t f2bf(float f) {               // RNE
    unsigned int u = __float_as_uint(f);
    u += 0x7fff + ((u >> 16) & 1);
    return (ushort_t)(u >> 16);
}
__device__ __forceinline__ float bf2f(ushort_t h) {
    return __uint_as_float(((unsigned int)h) << 16);
}
__device__ __forceinline__ float fast_tanh(float x) {             // sat-safe
    float e = __expf(2.0f * x);
    return 1.0f - 2.0f * __builtin_amdgcn_rcpf(e + 1.0f);
}
__device__ __forceinline__ float fast_sigmoid(float x) {
    return __builtin_amdgcn_rcpf(1.0f + __expf(-x));
}

__device__ __forceinline__ void load_lds_16(const void* g, void* l) {
    __builtin_amdgcn_global_load_lds(
        (const __attribute__((address_space(1))) void*)g,
        (__attribute__((address_space(3))) void*)l, 16, 0, 0);
}

// ---------------------------------------------------------------------------
// Tall 256x128 bf16 GEMM, BK=32, 8 waves (512 thr), 2-buffer, 2 blocks/CU.
// A: MxK bf16 row-major, Wt: NxK bf16 (W^T). K%64==0.
// Wave w: rows wr=(w>>1)*64, cols wc=(w&1)*64; 4x4 16x16 frags per wave.
// Stage per tile: A 1024 chunks (2/thread) + B 512 chunks (1/thread) =
// uniform 3 loads/thread. Loop: vmcnt(3) [tile t landed, t+1's 3 in
// flight] -> barrier -> ds_read 8xb128 -> lgkmcnt(0) -> barrier -> pin ->
// stage(t+2 -> buf just consumed) -> 16 MFMA. vmcnt never 0 mid-loop.
// Chunk-XOR swizzle pair identical to R0-R8 (bank-conflict-free verified).
// NO min-waves in launch_bounds: acc[4][4]=64 VGPR + frags must fit
// (R9 lesson: forcing 6 waves/SIMD -> 40 VGPRs -> 1 GB scratch spill).
// Epilogue modes: outp -> ig*tanh(v+res)+fg*bf16mem ; Cb -> bf16 ; Cf -> fp32.
// memb (bf16 mem rows in mpi layout): row b*8+s -> mpi row row+(row>>3).
// ---------------------------------------------------------------------------
__global__ __launch_bounds__(512)
void gemm256x128(const ushort_t* __restrict__ A, const ushort_t* __restrict__ Wt,
                 const float* __restrict__ bias, float* __restrict__ Cf,
                 ushort_t* __restrict__ Cb, const ushort_t* __restrict__ resb,
                 const float* __restrict__ igfg, const ushort_t* __restrict__ memb,
                 float* __restrict__ outp, int N, int K, int relu,
                 int ncol, int nrow)
{
    __shared__ __align__(16) ushort_t As[2][256][32];   // 32 KiB
    __shared__ __align__(16) ushort_t Bs[2][128][32];   // 16 KiB
    const int tid  = threadIdx.x;
    const int wave = tid >> 6, lane = tid & 63;
    const int lrow  = lane & 15;
    const int lquad = lane >> 4;
    const int wr = (wave >> 1) * 64;    // 0,64,128,192
    const int wc = (wave & 1)  * 64;    // 0,64

    // XCD-aware tile decode (row-tile's col-blocks at stride-8 ids -> same XCD)
    int l = blockIdx.x, rT, cT;
    if ((nrow & 7) == 0) {
        int group = l / (8 * ncol);
        int w     = l - group * 8 * ncol;
        rT = group * 8 + (w & 7);
        cT = w >> 3;
    } else {
        rT = l / ncol;
        cT = l - rT * ncol;
    }
    const int rowBase = rT * 256;
    const int colBase = cT * 128;

    // stage tile at k-offset k0 into buffer b: exactly 3 gload_lds/thread.
    auto stage = [&](int k0, int b) {
        #pragma unroll
        for (int i = 0; i < 2; ++i) {                    // A: 1024 chunks
            int e   = i * 512 + tid;
            int row = e >> 2, sl = e & 3;
            int gc  = sl ^ ((row >> 1) & 3);
            load_lds_16(A + (size_t)(rowBase + row) * K + k0 + gc * 8,
                        &As[b][row][sl * 8]);
        }
        {                                                // B: 512 chunks
            int e   = tid;
            int row = e >> 2, sl = e & 3;
            int gc  = sl ^ ((row >> 1) & 3);
            load_lds_16(Wt + (size_t)(colBase + row) * K + k0 + gc * 8,
                        &Bs[b][row][sl * 8]);
        }
    };

    const int NT = K >> 5;                  // K-steps of 32 (NT>=2)

    stage(0, 0);
    asm volatile("" ::: "memory");          // keep issue order = tile order
    stage(32, 1);

    f32x4_t acc[4][4] = {};

    for (int t = 0; t < NT; ++t) {
        const int b = t & 1;
        if (t + 1 < NT)
            asm volatile("s_waitcnt vmcnt(3)" ::: "memory");  // tile t landed
        else
            asm volatile("s_waitcnt vmcnt(0)" ::: "memory");
        __builtin_amdgcn_s_barrier();       // all waves: tile t visible

        bf16x8_t af[4], bfr[4];
        #pragma unroll
        for (int q = 0; q < 4; ++q) {
            int ma = wr + q * 16 + lrow;                  // 0..255
            int pa = lquad ^ ((ma >> 1) & 3);
            af[q]  = *(const bf16x8_t*)&As[b][ma][pa * 8];
            int nb = wc + q * 16 + lrow;                  // 0..127
            int pb = lquad ^ ((nb >> 1) & 3);
            bfr[q] = *(const bf16x8_t*)&Bs[b][nb][pb * 8];
        }
        asm volatile("s_waitcnt lgkmcnt(0)" ::: "memory");    // frags in regs
        __builtin_amdgcn_s_barrier();       // all waves done reading buf b
        __builtin_amdgcn_sched_barrier(0);  // pin: stage stays below barrier
        if (t + 2 < NT) stage((t + 2) * 32, b);               // refill buf b

        #pragma unroll
        for (int mi = 0; mi < 4; ++mi)
            #pragma unroll
            for (int ni = 0; ni < 4; ++ni)
                acc[mi][ni] = MFMA16(af[mi], bfr[ni], acc[mi][ni]);
    }

    // D layout: col = lane&15, row = lquad*4 + r   [m89/m91]
    #pragma unroll
    for (int mi = 0; mi < 4; ++mi) {
        #pragma unroll
        for (int ni = 0; ni < 4; ++ni) {
            int col = colBase + wc + ni * 16 + lrow;
            float bv = bias[col];
            #pragma unroll
            for (int r = 0; r < 4; ++r) {
                int row = rowBase + wr + mi * 16 + lquad * 4 + r;
                size_t idx = (size_t)row * N + col;
                float v = acc[mi][ni][r] + bv;
                if (resb) v += bf2f(resb[idx]);
                if (relu) v = fmaxf(v, 0.f);
                if (outp) {
                    float ig = igfg[row * 2], fg = igfg[row * 2 + 1];
                    float mv = bf2f(memb[(size_t)(row + (row >> 3)) * N + col]);
                    outp[idx] = ig * fast_tanh(v) + fg * mv;
                } else if (Cb) {
                    Cb[idx] = f2bf(v);
                } else {
                    Cf[idx] = v;
                }
            }
        }
    }
}

// ---------------------------------------------------------------------------
// 128x128 bf16 GEMM, BK=32, 4 waves, 3-buffer 3-deep prefetch (x GEMM).
// ---------------------------------------------------------------------------
__global__ __launch_bounds__(256, 3)
void gemm128p3(const ushort_t* __restrict__ A, const ushort_t* __restrict__ Wt,
               const float* __restrict__ bias, ushort_t* __restrict__ Cb,
               int N, int K, int ncol, int nrow)
{
    __shared__ __align__(16) ushort_t As[3][128][32];   // 24 KiB
    __shared__ __align__(16) ushort_t Bs[3][128][32];   // 24 KiB
    const int tid  = threadIdx.x;
    const int wave = tid >> 6, lane = tid & 63;
    const int wr = (wave >> 1) * 64;
    const int wc = (wave & 1)  * 64;
    const int lrow  = lane & 15;
    const int lquad = lane >> 4;

    int l = blockIdx.x, rT, cT;
    if ((nrow & 7) == 0) {
        int group = l / (8 * ncol);
        int w     = l - group * 8 * ncol;
        rT = group * 8 + (w & 7);
        cT = w >> 3;
    } else {
        rT = l / ncol;
        cT = l - rT * ncol;
    }
    const int rowBase = rT * 128;
    const int colBase = cT * 128;

    auto stage = [&](int k0, int b) {
        #pragma unroll
        for (int i = 0; i < 2; ++i) {
            int e   = i * 256 + tid;
            int row = e >> 2, sl = e & 3;
            int gc  = sl ^ ((row >> 1) & 3);
            load_lds_16(A + (size_t)(rowBase + row) * K + k0 + gc * 8,
                        &As[b][row][sl * 8]);
        }
        #pragma unroll
        for (int i = 0; i < 2; ++i) {
            int e   = i * 256 + tid;
            int row = e >> 2, sl = e & 3;
            int gc  = sl ^ ((row >> 1) & 3);
            load_lds_16(Wt + (size_t)(colBase + row) * K + k0 + gc * 8,
                        &Bs[b][row][sl * 8]);
        }
    };

    const int NT = K >> 5;

    stage(0, 0);
    asm volatile("" ::: "memory");
    if (NT > 1) stage(32, 1);
    asm volatile("" ::: "memory");
    if (NT > 2) stage(64, 2);

    f32x4_t acc[4][4] = {};

    for (int t = 0; t < NT; ++t) {
        const int b = t % 3;
        if (t + 2 < NT)
            asm volatile("s_waitcnt vmcnt(8)" ::: "memory");
        else if (t + 1 < NT)
            asm volatile("s_waitcnt vmcnt(4)" ::: "memory");
        else
            asm volatile("s_waitcnt vmcnt(0)" ::: "memory");
        __builtin_amdgcn_s_barrier();

        bf16x8_t af[4], bfr[4];
        #pragma unroll
        for (int q = 0; q < 4; ++q) {
            int ma = wr + q * 16 + lrow;
            int pa = lquad ^ ((ma >> 1) & 3);
            af[q]  = *(const bf16x8_t*)&As[b][ma][pa * 8];
            int nb = wc + q * 16 + lrow;
            int pb = lquad ^ ((nb >> 1) & 3);
            bfr[q] = *(const bf16x8_t*)&Bs[b][nb][pb * 8];
        }
        asm volatile("s_waitcnt lgkmcnt(0)" ::: "memory");
        __builtin_amdgcn_s_barrier();
        __builtin_amdgcn_sched_barrier(0);
        if (t + 3 < NT) stage((t + 3) * 32, b);

        #pragma unroll
        for (int mi = 0; mi < 4; ++mi)
            #pragma unroll
            for (int ni = 0; ni < 4; ++ni)
                acc[mi][ni] = MFMA16(af[mi], bfr[ni], acc[mi][ni]);
    }

    #pragma unroll
    for (int mi = 0; mi < 4; ++mi) {
        #pragma unroll
        for (int ni = 0; ni < 4; ++ni) {
            int col = colBase + wc + ni * 16 + lrow;
            float bv = bias[col];
            #pragma unroll
            for (int r = 0; r < 4; ++r) {
                int row = rowBase + wr + mi * 16 + lquad * 4 + r;
                Cb[(size_t)row * N + col] = f2bf(acc[mi][ni][r] + bv);
            }
        }
    }
}

// ---------------------------------------------------------------------------
// 256x256 8-phase bf16 GEMM (qkv only; control arm, ~110us/chunk).
// ---------------------------------------------------------------------------
__global__ __launch_bounds__(512, 2)
void gemm256(const ushort_t* __restrict__ A, const ushort_t* __restrict__ Wt,
             const float* __restrict__ bias, ushort_t* __restrict__ Cb,
             int N, int K, int ncol, int nrow)
{
    __shared__ __align__(16) ushort_t As[2][256][64];   // 64 KiB
    __shared__ __align__(16) ushort_t Bs[2][256][64];   // 64 KiB

    const int tid   = threadIdx.x;
    const int wave  = tid >> 6, lane = tid & 63;
    const int lrow  = lane & 15, lquad = lane >> 4;
    const int wr    = (wave >> 2) * 64;
    const int wc    = (wave & 3) * 32;

    const int nwg = ncol * nrow;
    int l = blockIdx.x;
    int q = nwg >> 3, r = nwg & 7;
    int xcd = l & 7, ib = l >> 3;
    int wg = (xcd < r) ? xcd * (q + 1) + ib : r * (q + 1) + (xcd - r) * q + ib;
    int rT = wg / ncol, cT = wg - rT * ncol;
    const int rowBase = rT * 256;
    const int colBase = cT * 256;

    const int NT = K >> 6;

    auto stage = [&](const ushort_t* __restrict__ G, int gbase, int kt,
                     int half, ushort_t (*lds)[64]) {
        #pragma unroll
        for (int j = 0; j < 2; ++j) {
            int ci   = j * 512 + tid;
            int rl   = ci >> 3;
            int slot = ci & 7;
            int row  = half * 128 + rl;
            int gc   = slot ^ (rl & 7);
            const ushort_t* g = G + (size_t)(gbase + row) * K + kt * 64 + gc * 8;
            load_lds_16(g, &lds[row][slot * 8]);
        }
    };

    stage(A,  rowBase, 0, 0, As[0]);
    stage(A,  rowBase, 0, 1, As[0]);
    stage(Wt, colBase, 0, 0, Bs[0]);
    stage(Wt, colBase, 0, 1, Bs[0]);
    asm volatile("" ::: "memory");
    stage(A,  rowBase, 1, 0, As[1]);
    stage(Wt, colBase, 1, 0, Bs[1]);
    asm volatile("s_waitcnt vmcnt(4)" ::: "memory");
    __builtin_amdgcn_s_barrier();

    f32x4_t acc[8][4] = {};
    bf16x8_t af[4][2], bfr[4][2];
    const int s0 = (lquad ^ (lrow & 7)) * 8;
    const int s1 = ((lquad ^ (lrow & 7)) ^ 4) * 8;

    for (int t = 0; t < NT; ++t) {
        const int bf = t & 1, nf = bf ^ 1;
        ushort_t (*Ab)[64] = As[bf];
        ushort_t (*Bb)[64] = Bs[bf];

        #pragma unroll
        for (int m = 0; m < 4; ++m) {
            int ra = wr + m * 16 + lrow;
            af[m][0] = *(const bf16x8_t*)&Ab[ra][s0];
            af[m][1] = *(const bf16x8_t*)&Ab[ra][s1];
        }
        #pragma unroll
        for (int n = 0; n < 2; ++n) {
            int rb = wc + n * 16 + lrow;
            bfr[n][0] = *(const bf16x8_t*)&Bb[rb][s0];
            bfr[n][1] = *(const bf16x8_t*)&Bb[rb][s1];
        }
        if (t + 1 < NT) stage(A, rowBase, t + 1, 1, As[nf]);
        __builtin_amdgcn_s_barrier();
        asm volatile("s_waitcnt lgkmcnt(0)" ::: "memory");
        __builtin_amdgcn_s_setprio(1);
        #pragma unroll
        for (int m = 0; m < 4; ++m)
            #pragma unroll
            for (int n = 0; n < 2; ++n) {
                acc[m][n] = MFMA16(af[m][0], bfr[n][0], acc[m][n]);
                acc[m][n] = MFMA16(af[m][1], bfr[n][1], acc[m][n]);
            }
        __builtin_amdgcn_s_setprio(0);
        __builtin_amdgcn_s_barrier();

        #pragma unroll
        for (int n = 0; n < 2; ++n) {
            int rb = 128 + wc + n * 16 + lrow;
            bfr[2 + n][0] = *(const bf16x8_t*)&Bb[rb][s0];
            bfr[2 + n][1] = *(const bf16x8_t*)&Bb[rb][s1];
        }
        if (t + 1 < NT) stage(Wt, colBase, t + 1, 1, Bs[nf]);
        __builtin_amdgcn_s_barrier();
        asm volatile("s_waitcnt lgkmcnt(0)" ::: "memory");
        __builtin_amdgcn_s_setprio(1);
        #pragma unroll
        for (int m = 0; m < 4; ++m)
            #pragma unroll
            for (int n = 0; n < 2; ++n) {
                acc[m][2 + n] = MFMA16(af[m][0], bfr[2 + n][0], acc[m][2 + n]);
                acc[m][2 + n] = MFMA16(af[m][1], bfr[2 + n][1], acc[m][2 + n]);
            }
        __builtin_amdgcn_s_setprio(0);
        __builtin_amdgcn_s_barrier();

        #pragma unroll
        for (int m = 0; m < 4; ++m) {
            int ra = 128 + wr + m * 16 + lrow;
            af[m][0] = *(const bf16x8_t*)&Ab[ra][s0];
            af[m][1] = *(const bf16x8_t*)&Ab[ra][s1];
        }
        if (t + 2 < NT) stage(A, rowBase, t + 2, 0, As[bf]);
        __builtin_amdgcn_s_barrier();
        asm volatile("s_waitcnt lgkmcnt(0)" ::: "memory");
        __builtin_amdgcn_s_setprio(1);
        #pragma unroll
        for (int m = 0; m < 4; ++m)
            #pragma unroll
            for (int n = 0; n < 2; ++n) {
                acc[4 + m][n] = MFMA16(af[m][0], bfr[n][0], acc[4 + m][n]);
                acc[4 + m][n] = MFMA16(af[m][1], bfr[n][1], acc[4 + m][n]);
            }
        __builtin_amdgcn_s_setprio(0);
        __builtin_amdgcn_s_barrier();

        if (t + 2 < NT) {
            stage(Wt, colBase, t + 2, 0, Bs[bf]);
            asm volatile("s_waitcnt vmcnt(4)" ::: "memory");
        } else if (t + 1 < NT) {
            asm volatile("s_waitcnt vmcnt(0)" ::: "memory");
        }
        __builtin_amdgcn_s_barrier();
        __builtin_amdgcn_s_setprio(1);
        #pragma unroll
        for (int m = 0; m < 4; ++m)
            #pragma unroll
            for (int n = 0; n < 2; ++n) {
                acc[4 + m][2 + n] = MFMA16(af[m][0], bfr[2 + n][0], acc[4 + m][2 + n]);
                acc[4 + m][2 + n] = MFMA16(af[m][1], bfr[2 + n][1], acc[4 + m][2 + n]);
            }
        __builtin_amdgcn_s_setprio(0);
        __builtin_amdgcn_s_barrier();
    }

    #pragma unroll
    for (int mi = 0; mi < 8; ++mi) {
        #pragma unroll
        for (int ni = 0; ni < 4; ++ni) {
            int col = colBase + wc + (ni & 1) * 16 + ((ni >> 1) << 7) + lrow;
            float bv = bias[col];
            #pragma unroll
            for (int rr = 0; rr < 4; ++rr) {
                int row = rowBase + wr + (mi & 3) * 16 + ((mi >> 2) << 7)
                        + lquad * 4 + rr;
                size_t idx = (size_t)row * N + col;
                Cb[idx] = f2bf(acc[mi][ni][rr] + bv);
            }
        }
    }
}

// ---------------------------------------------------------------------------
// fp32 -> bf16 elementwise
// ---------------------------------------------------------------------------
__global__ __launch_bounds__(256)
void conv_bf16(const float* __restrict__ in, ushort_t* __restrict__ out, size_t n)
{
    size_t i = ((size_t)blockIdx.x * 256 + threadIdx.x) * 4;
    if (i >= n) return;
    float4 v = *(const float4*)(in + i);
    out[i + 0] = f2bf(v.x); out[i + 1] = f2bf(v.y);
    out[i + 2] = f2bf(v.z); out[i + 3] = f2bf(v.w);
}

// ---------------------------------------------------------------------------
// Weight transpose+convert, all 4 weights in one launch.
// x-ranges: [0,32)=kernel_in, [32,128)=kernel_qkv, [128,160)=k0, [160,192)=k1
// ---------------------------------------------------------------------------
__global__ __launch_bounds__(256)
void conv_wt4(const float* __restrict__ W0, ushort_t* __restrict__ T0,
              const float* __restrict__ W1, ushort_t* __restrict__ T1,
              const float* __restrict__ W2, ushort_t* __restrict__ T2,
              const float* __restrict__ W3, ushort_t* __restrict__ T3)
{
    __shared__ float t[32][33];
    int bx = blockIdx.x;
    const float* W; ushort_t* T; int N;
    if (bx < 32)       { W = W0; T = T0; N = 1024; }
    else if (bx < 128) { W = W1; T = T1; N = 3072; bx -= 32; }
    else if (bx < 160) { W = W2; T = T2; N = 1024; bx -= 128; }
    else               { W = W3; T = T3; N = 1024; bx -= 160; }
    const int K = 1024;
    const int n0 = bx * 32, k0 = blockIdx.y * 32;
    const int tx = threadIdx.x & 31, ty = threadIdx.x >> 5;   // (32, 8)
    #pragma unroll
    for (int i = 0; i < 4; ++i)
        t[ty * 4 + i][tx] = W[(size_t)(k0 + ty * 4 + i) * N + n0 + tx];
    __syncthreads();
    #pragma unroll
    for (int i = 0; i < 4; ++i)
        T[(size_t)(n0 + ty * 4 + i) * K + k0 + tx] = f2bf(t[tx][ty * 4 + i]);
}

// ---------------------------------------------------------------------------
// prep: block per mpi row (b*9+s). s<8: mem row -> mpi bf16 + fused gates
// reduction tanh(mem).kgm -> igfg. s==8: copy x_b row.
// ---------------------------------------------------------------------------
__global__ __launch_bounds__(256)
void prep_kernel(const float* __restrict__ mem, const ushort_t* __restrict__ xb,
                 const float* __restrict__ kgm, const float* __restrict__ bgm,
                 const float* __restrict__ gi, ushort_t* __restrict__ mpi,
                 float* __restrict__ igfg)
{
    const int row = blockIdx.x;            // b*9+s
    const int tid = threadIdx.x;
    const int b = row / 9, s = row - b * 9;
    if (s == 8) {
        ((ushort4*)(mpi + (size_t)row * 1024))[tid] =
            ((const ushort4*)(xb + (size_t)b * 1024))[tid];
        return;
    }
    const float* mrow = mem + ((size_t)b * 8 + s) * 1024;
    float4 v = ((const float4*)mrow)[tid];
    ushort4 o;
    o.x = f2bf(v.x); o.y = f2bf(v.y); o.z = f2bf(v.z); o.w = f2bf(v.w);
    ((ushort4*)(mpi + (size_t)row * 1024))[tid] = o;
    float4 k0 = ((const float4*)kgm)[tid * 2];
    float4 k1 = ((const float4*)kgm)[tid * 2 + 1];
    float t0 = fast_tanh(v.x), t1 = fast_tanh(v.y);
    float t2 = fast_tanh(v.z), t3 = fast_tanh(v.w);
    float g0 = t0 * k0.x + t1 * k0.z + t2 * k1.x + t3 * k1.z;
    float g1 = t0 * k0.y + t1 * k0.w + t2 * k1.y + t3 * k1.w;
    #pragma unroll
    for (int m = 1; m <= 32; m <<= 1) {
        g0 += __shfl_xor(g0, m);
        g1 += __shfl_xor(g1, m);
    }
    __shared__ float wg[4][2];
    if ((tid & 63) == 0) { wg[tid >> 6][0] = g0; wg[tid >> 6][1] = g1; }
    __syncthreads();
    if (tid == 0) {
        float G0 = wg[0][0] + wg[1][0] + wg[2][0] + wg[3][0];
        float G1 = wg[0][1] + wg[1][1] + wg[2][1] + wg[3][1];
        int orow = b * 8 + s;
        igfg[orow * 2 + 0] = fast_sigmoid(G0 + bgm[0] + gi[b * 2 + 0]);
        igfg[orow * 2 + 1] = fast_sigmoid(G1 + bgm[1] + gi[b * 2 + 1] + 1.0f);
    }
}

// ---------------------------------------------------------------------------
// MFMA attention: block per (b,h), 256 thr. Residual from mpi bf16.
// ---------------------------------------------------------------------------
__global__ __launch_bounds__(256)
void attn_kernel(const ushort_t* __restrict__ qkv, const ushort_t* __restrict__ mpib,
                 ushort_t* __restrict__ m1b)
{
    const int bh = blockIdx.x;
    const int b = bh >> 3, h = bh & 7;
    constexpr int VS = 40;                            // padded j-stride
    __shared__ __align__(16) ushort_t vt[128 * VS];   // V^T [d][j]
    __shared__ __align__(16) ushort_t pw[16 * VS];    // P [i][j]
    const int tid  = threadIdx.x;
    const int lane = tid & 63, wave = tid >> 6;
    const int quad = lane >> 4;
    const size_t qrow0 = (size_t)b * 9;

    {
        unsigned long long* z = (unsigned long long*)vt;
        #pragma unroll
        for (int i = 0; i < 5; ++i) z[tid + i * 256] = 0ull;
        if (tid < 160) ((unsigned long long*)pw)[tid] = 0ull;
    }
    __syncthreads();
    for (int c = tid; c < 9 * 128; c += 256) {
        int j = c >> 7, d = c & 127;
        vt[d * VS + j] = qkv[(qrow0 + j) * 3072 + (size_t)h * 384 + 256 + d];
    }

    f32x4_t sacc = {0.f, 0.f, 0.f, 0.f};
    if (wave == 0) {
        const int m  = lane & 7;
        const int n  = lane & 15;
        const int nc = n > 8 ? 8 : n;
        const ushort_t* qb = qkv + (qrow0 + m)  * 3072 + (size_t)h * 384 + quad * 8;
        const ushort_t* kb = qkv + (qrow0 + nc) * 3072 + (size_t)h * 384 + 128 + quad * 8;
        #pragma unroll
        for (int t = 0; t < 4; ++t) {
            bf16x8_t aq = *(const bf16x8_t*)(qb + t * 32);
            bf16x8_t bk = *(const bf16x8_t*)(kb + t * 32);
            sacc = __builtin_amdgcn_mfma_f32_16x16x32_bf16(aq, bk, sacc, 0, 0, 0);
        }
    }
    __syncthreads();

    if (wave == 0) {
        const int j = lane & 15;
        const float scale = 0.05103103630798288f;      // 384^-0.5
        #pragma unroll
        for (int r = 0; r < 4; ++r) {
            float sv = (j < 9) ? sacc[r] * scale : -1e30f;
            float mx = sv;
            mx = fmaxf(mx, __shfl_xor(mx, 1));
            mx = fmaxf(mx, __shfl_xor(mx, 2));
            mx = fmaxf(mx, __shfl_xor(mx, 4));
            mx = fmaxf(mx, __shfl_xor(mx, 8));
            float e = (j < 9) ? __expf(sv - mx) : 0.f;
            float sum = e;
            sum += __shfl_xor(sum, 1);
            sum += __shfl_xor(sum, 2);
            sum += __shfl_xor(sum, 4);
            sum += __shfl_xor(sum, 8);
            pw[(quad * 4 + r) * VS + j] = f2bf(e * __builtin_amdgcn_rcpf(sum));
        }
    }
    __syncthreads();

    {
        const int n  = lane & 15;
        const int d0 = wave * 32;
        bf16x8_t pa = *(const bf16x8_t*)&pw[n * VS + quad * 8];
        #pragma unroll
        for (int g = 0; g < 2; ++g) {
            int d = d0 + g * 16 + n;
            bf16x8_t vb = *(const bf16x8_t*)&vt[d * VS + quad * 8];
            f32x4_t o = {0.f, 0.f, 0.f, 0.f};
            o = __builtin_amdgcn_mfma_f32_16x16x32_bf16(pa, vb, o, 0, 0, 0);
            #pragma unroll
            for (int r = 0; r < 4; ++r) {
                int i = quad * 4 + r;
                if (i < 8) {
                    float mv = bf2f(mpib[((size_t)b * 9 + i) * 1024 + (size_t)h * 128 + d]);
                    size_t idx = ((size_t)b * 8 + i) * 1024 + (size_t)h * 128 + d;
                    m1b[idx] = f2bf(o[r] + mv);
                }
            }
        }
    }
}

// ---------------------------------------------------------------------------
// gi[b][g] = x_b[b,:] . kernel_gi[:,g] + bias_gi[g]
// ---------------------------------------------------------------------------
__global__ __launch_bounds__(256)
void gi_kernel(const ushort_t* __restrict__ xb, const float* __restrict__ kgi,
               const float* __restrict__ bgi, float* __restrict__ gi)
{
    const int b = blockIdx.x, tid = threadIdx.x;
    float g0 = 0.f, g1 = 0.f;
    for (int k = tid; k < 1024; k += 256) {
        float xv = bf2f(xb[(size_t)b * 1024 + k]);
        g0 += xv * kgi[k * 2];
        g1 += xv * kgi[k * 2 + 1];
    }
    #pragma unroll
    for (int m = 1; m <= 32; m <<= 1) {
        g0 += __shfl_xor(g0, m);
        g1 += __shfl_xor(g1, m);
    }
    __shared__ float wg[4][2];
    if ((tid & 63) == 0) { wg[tid >> 6][0] = g0; wg[tid >> 6][1] = g1; }
    __syncthreads();
    if (tid == 0) {
        gi[b * 2 + 0] = wg[0][0] + wg[1][0] + wg[2][0] + wg[3][0] + bgi[0];
        gi[b * 2 + 1] = wg[0][1] + wg[1][1] + wg[2][1] + wg[3][1] + bgi[1];
    }
}

// ---------------------------------------------------------------------------
extern "C" void kernel_launch(void* const* d_in, const int* in_sizes, int n_in,
                              void* d_out, int out_size, void* d_ws, size_t ws_size,
                              hipStream_t stream)
{
    const float* inputs     = (const float*)d_in[0];
    const float* memory     = (const float*)d_in[1];
    const float* kernel_qkv = (const float*)d_in[2];
    const float* bias_qkv   = (const float*)d_in[3];
    const float* kernel_gi  = (const float*)d_in[4];
    const float* bias_gi    = (const float*)d_in[5];
    const float* kernel_gm  = (const float*)d_in[6];
    const float* bias_gm    = (const float*)d_in[7];
    const float* kernel_in  = (const float*)d_in[8];
    const float* bias_in    = (const float*)d_in[9];
    const float* mlp_k0     = (const float*)d_in[10];
    const float* mlp_b0     = (const float*)d_in[11];
    const float* mlp_k1     = (const float*)d_in[12];
    const float* mlp_b1     = (const float*)d_in[13];
    float* out = (float*)d_out;

    // ---- workspace carve (bytes) ----
    char* p = (char*)d_ws;
    ushort_t* in_b   = (ushort_t*)p;  p += (size_t)2048 * 1024 * 2;    // 4 MB
    ushort_t* x_b    = (ushort_t*)p;  p += (size_t)2048 * 1024 * 2;    // 4 MB
    ushort_t* wt_in  = (ushort_t*)p;  p += (size_t)1024 * 1024 * 2;    // 2 MB
    ushort_t* wt_qkv = (ushort_t*)p;  p += (size_t)3072 * 1024 * 2;    // 6 MB
    ushort_t* wt_k0  = (ushort_t*)p;  p += (size_t)1024 * 1024 * 2;
    ushort_t* wt_k1  = (ushort_t*)p;  p += (size_t)1024 * 1024 * 2;
    float*    ws_gi  = (float*)p;     p += (size_t)2048 * 2 * 4;
    float*    igfg   = (float*)p;     p += (size_t)16384 * 2 * 4;      // 128 KB
    ushort_t* ws_mpi = (ushort_t*)p;  p += (size_t)18432 * 1024 * 2;   // 36 MB
    ushort_t* m1b    = (ushort_t*)p;  p += (size_t)16384 * 1024 * 2;   // 32 MB
    ushort_t* ws_h   = (ushort_t*)p;  p += (size_t)16384 * 1024 * 2;   // 32 MB
    size_t fixed = (size_t)(p - (char*)d_ws);

    // Bc*9 must be divisible by 256 for the 256^2 kernel => Bc >= 256.
    int Bc = 256;
    for (int cand = 1024; cand >= 256; cand >>= 1)
        if (fixed + (size_t)cand * 9 * 3072 * 2 <= ws_size) { Bc = cand; break; }
    ushort_t* ws_qkv = (ushort_t*)p;   // Bc*9*3072 bf16

    // ---- conversions ----
    conv_bf16<<<2048, 256, 0, stream>>>(inputs, in_b, (size_t)2048 * 1024);
    conv_wt4<<<dim3(192, 32), 256, 0, stream>>>(
        kernel_in, wt_in, kernel_qkv, wt_qkv, mlp_k0, wt_k0, mlp_k1, wt_k1);

    // x_b = bf16(inputs @ kernel_in + bias_in)
    gemm128p3<<<16 * 8, 256, 0, stream>>>(
        in_b, wt_in, bias_in, x_b, 1024, 1024, 8, 16);

    gi_kernel<<<2048, 256, 0, stream>>>(x_b, kernel_gi, bias_gi, ws_gi);
    prep_kernel<<<18432, 256, 0, stream>>>(memory, x_b, kernel_gm, bias_gm,
                                           ws_gi, ws_mpi, igfg);

    // qkv + attention, chunked (256^2 8-phase GEMM, control arm)
    const int NC = 2048 / Bc;
    for (int c = 0; c < NC; ++c) {
        const int b0 = c * Bc;
        const int nrow = Bc * 9 / 256;
        gemm256<<<12 * nrow, 512, 0, stream>>>(
            ws_mpi + (size_t)b0 * 9 * 1024, wt_qkv, bias_qkv, ws_qkv,
            3072, 1024, 12, nrow);
        attn_kernel<<<Bc * 8, 256, 0, stream>>>(
            ws_qkv, ws_mpi + (size_t)b0 * 9 * 1024, m1b + (size_t)b0 * 8192);
    }

    // h = relu(m1 @ mlp_k0 + mlp_b0)   (tall 256x128: 512 blocks, 2/CU)
    gemm256x128<<<64 * 8, 512, 0, stream>>>(
        m1b, wt_k0, mlp_b0, nullptr, ws_h, nullptr, nullptr, nullptr, nullptr,
        1024, 1024, 1, 8, 64);

    // out = ig*tanh(m1 + h @ mlp_k1 + mlp_b1) + fg*mem(bf16 via mpi), fused
    gemm256x128<<<64 * 8, 512, 0, stream>>>(
        ws_h, wt_k1, mlp_b1, nullptr, nullptr, m1b, igfg, ws_mpi, out,
        1024, 1024, 0, 8, 64);
}